// Round 5
// baseline (128.517 us; speedup 1.0000x reference)
//
#include <hip/hip_runtime.h>

typedef __bf16 bf16x8 __attribute__((ext_vector_type(8)));
typedef __bf16 bf16x4 __attribute__((ext_vector_type(4)));
typedef float floatx4 __attribute__((ext_vector_type(4)));
typedef float f32x2  __attribute__((ext_vector_type(2)));

#define NENT 237
#define NREL 237
#define D 128
#define B_TRIPLES 16384
#define LDSP 72   // 64 k-elements + 8 pad (144 B pitch -> uniform bank rotation on b128 reads)

// proj[r][e][j] = sum_d ent_emb[e][d] * rel_W[r][d][j]
// Measured-best shape: one block per (128-row slab, relation); 474 blocks x 256
// threads, 36.9 KB LDS (4 blocks/CU capable -> cross-block overlap hides the
// barrier drains).  Two-phase K staging (64+64).  Conflict-free lane-per-k sW
// mapping: store bank = (4n + k/2)%32 spans all 32 banks, adjacent lanes merge
// in one 4B word.
__global__ __launch_bounds__(256) void proj_gemm(
    const float* __restrict__ ent_emb,   // (N, 128) fp32, only rows <256 touched
    const float* __restrict__ rel_W,     // (237, 128, 128) fp32
    float* __restrict__ proj)            // (237, 237, 128) fp32 (workspace)
{
  const int r   = blockIdx.y;
  const int m0  = blockIdx.x * 128;      // 0 or 128
  const int tid = threadIdx.x;

  __shared__ __bf16 sE[128 * LDSP];      // A: sE[m][k]   (row-major, k contiguous)
  __shared__ __bf16 sW[128 * LDSP];      // B^T: sW[n][k] = W[k][n]

  const int wave = tid >> 6;
  const int lane = tid & 63;
  const int lrow = lane & 15;
  const int quad = lane >> 4;
  const int r0 = wave * 32;              // wave's 32-row stripe

  floatx4 acc[2][8];
#pragma unroll
  for (int tr = 0; tr < 2; ++tr)
#pragma unroll
    for (int tc = 0; tc < 8; ++tc)
      acc[tr][tc] = (floatx4){0.f, 0.f, 0.f, 0.f};

  for (int kh = 0; kh < 2; ++kh) {
    if (kh) __syncthreads();             // MFMA reads of prev half done

    // --- stage E (fp32 -> bf16), 128 rows x 64 k ---
    {
      const int row  = tid >> 1;           // 0..127
      const int half = (tid & 1) * 32;     // k sub-offset
      const float* src = ent_emb + (size_t)(m0 + row) * D + kh * 64 + half;
      __bf16* dst = sE + row * LDSP + half;
#pragma unroll
      for (int i = 0; i < 8; ++i) {
        float4 v = ((const float4*)src)[i];
        bf16x4 pk = { (__bf16)v.x, (__bf16)v.y, (__bf16)v.z, (__bf16)v.w };
        *(bf16x4*)(dst + i * 4) = pk;
      }
    }
    // --- stage W transposed (fp32 -> bf16): sW[n][k] = W[kh*64+k][n] ---
    {
      const int k  = tid & 63;             // k within half (= lane)
      const int n0 = (tid >> 6) * 32;      // wave's 32-col chunk
      const float* src = rel_W + ((size_t)r * D + kh * 64 + k) * D + n0;
#pragma unroll
      for (int i = 0; i < 8; ++i) {
        float4 v = ((const float4*)src)[i];
        const int n = n0 + i * 4;
        sW[(n + 0) * LDSP + k] = (__bf16)v.x;
        sW[(n + 1) * LDSP + k] = (__bf16)v.y;
        sW[(n + 2) * LDSP + k] = (__bf16)v.z;
        sW[(n + 3) * LDSP + k] = (__bf16)v.w;
      }
    }
    __syncthreads();

    // --- MFMA: 2 k-steps of 32 over this half ---
#pragma unroll
    for (int kk = 0; kk < 2; ++kk) {
      const int k0 = kk * 32 + quad * 8;
      bf16x8 a[2], b[8];
#pragma unroll
      for (int tr = 0; tr < 2; ++tr)
        a[tr] = *(const bf16x8*)&sE[(r0 + tr * 16 + lrow) * LDSP + k0];
#pragma unroll
      for (int tc = 0; tc < 8; ++tc)
        b[tc] = *(const bf16x8*)&sW[(tc * 16 + lrow) * LDSP + k0];
#pragma unroll
      for (int tr = 0; tr < 2; ++tr)
#pragma unroll
        for (int tc = 0; tc < 8; ++tc)
          acc[tr][tc] = __builtin_amdgcn_mfma_f32_16x16x32_bf16(
              a[tr], b[tc], acc[tr][tc], 0, 0, 0);
    }
  }

  // --- store: D[m][n], m = quad*4 + reg (verified m89/m91 layout), n = lrow ---
#pragma unroll
  for (int tr = 0; tr < 2; ++tr) {
    const int ebase = m0 + r0 + tr * 16 + quad * 4;
#pragma unroll
    for (int reg = 0; reg < 4; ++reg) {
      const int e = ebase + reg;
      if (e < NENT) {
        float* dst = proj + ((size_t)r * NENT + e) * D;
#pragma unroll
        for (int tc = 0; tc < 8; ++tc)
          dst[tc * 16 + lrow] = acc[tr][tc][reg];
      }
    }
  }
}

// out[b] = fc_b + sum_{c,j} relu(w0[c]*ph[j] + w1[c]*re[j] + w2[c]*pt[j] + cb[c]) * fcw[c*128+j]
// One wave per triple, NO LDS, NO barrier -> 8 blocks/CU, 32 waves/CU (the
// empirically-best occupancy shape from r0).  Lane l handles dims j = 2l, 2l+1:
// every fc_w access is ONE dwordx2 (50 loads vs r0's 100), gathers are 3
// dwordx2 (vs 6 dword), math is packed f32x2 (v_pk_fma_f32, half r0's VALU).
__global__ __launch_bounds__(256) void conv_fc(
    const int*   __restrict__ triples,   // (B,3)
    const float* __restrict__ rel_emb,   // (237,128)
    const float* __restrict__ conv_w,    // (50,3)
    const float* __restrict__ conv_b,    // (50)
    const float* __restrict__ fc_w,      // (6400)
    const float* __restrict__ fc_b,      // (1)
    const float* __restrict__ proj,      // (237,237,128)
    float*       __restrict__ out)       // (B,)
{
  const int tid  = threadIdx.x;
  const int wave = tid >> 6;
  const int lane = tid & 63;
  const int b    = blockIdx.x * 4 + wave;

  const int h = triples[b * 3 + 0];
  const int r = triples[b * 3 + 1];
  const int t = triples[b * 3 + 2];

  // j = 2*lane, 2*lane+1 (all rows 512B-aligned -> float2 loads legal)
  const float2* ph2 = (const float2*)(proj + ((size_t)r * NENT + h) * D);
  const float2* pt2 = (const float2*)(proj + ((size_t)r * NENT + t) * D);
  const float2* re2 = (const float2*)(rel_emb + (size_t)r * D);
  const float2* fw2 = (const float2*)fc_w;   // fw2[c*64 + lane] = fc_w[c*128 + 2*lane ..]

  const float2 vph_ = ph2[lane];
  const float2 vpt_ = pt2[lane];
  const float2 vre_ = re2[lane];
  f32x2 vph = { vph_.x, vph_.y };
  f32x2 vpt = { vpt_.x, vpt_.y };
  f32x2 vre = { vre_.x, vre_.y };

  f32x2 acc = (f32x2){0.f, 0.f};
#pragma unroll 10
  for (int c = 0; c < 50; ++c) {
    const float w0 = conv_w[c * 3 + 0];
    const float w1 = conv_w[c * 3 + 1];
    const float w2 = conv_w[c * 3 + 2];
    const float bc = conv_b[c];
    const float2 fwc = fw2[c * 64 + lane];          // one dwordx2 per channel
    f32x2 f = vph * w0 + vre * w1 + vpt * w2 + bc;  // packed fma chain
    f.x = fmaxf(f.x, 0.f);
    f.y = fmaxf(f.y, 0.f);
    acc.x = fmaf(f.x, fwc.x, acc.x);
    acc.y = fmaf(f.y, fwc.y, acc.y);
  }
  float a = acc.x + acc.y;
#pragma unroll
  for (int off = 32; off; off >>= 1) a += __shfl_down(a, off, 64);
  if (lane == 0) out[b] = a + fc_b[0];
}

extern "C" void kernel_launch(void* const* d_in, const int* in_sizes, int n_in,
                              void* d_out, int out_size, void* d_ws, size_t ws_size,
                              hipStream_t stream) {
  const int*   triples = (const int*)  d_in[0];
  const float* ent_emb = (const float*)d_in[1];
  const float* rel_emb = (const float*)d_in[2];
  const float* rel_W   = (const float*)d_in[3];
  const float* conv_w  = (const float*)d_in[4];
  const float* conv_b  = (const float*)d_in[5];
  const float* fc_w    = (const float*)d_in[6];
  const float* fc_b    = (const float*)d_in[7];
  float* out  = (float*)d_out;
  float* proj = (float*)d_ws;            // 237*237*128 fp32 = 28.8 MB

  dim3 g1(2, NREL);
  proj_gemm<<<g1, 256, 0, stream>>>(ent_emb, rel_W, proj);
  conv_fc<<<B_TRIPLES / 4, 256, 0, stream>>>(triples, rel_emb, conv_w, conv_b,
                                             fc_w, fc_b, proj, out);
}

// Round 6
// 122.558 us; speedup vs baseline: 1.0486x; 1.0486x over previous
//
#include <hip/hip_runtime.h>

typedef __bf16 bf16x8 __attribute__((ext_vector_type(8)));
typedef __bf16 bf16x4 __attribute__((ext_vector_type(4)));
typedef __bf16 bf16x2 __attribute__((ext_vector_type(2)));
typedef float floatx4 __attribute__((ext_vector_type(4)));
typedef float f32x2  __attribute__((ext_vector_type(2)));

#define NENT 237
#define NREL 237
#define D 128
#define B_TRIPLES 16384
#define LDSP 72   // 64 k-elements + 8 pad (144 B pitch -> uniform bank rotation on b128 reads)

// proj[r][e][j] = sum_d ent_emb[e][d] * rel_W[r][d][j], stored BF16.
// Measured-best shape: one block per (128-row slab, relation); 474 blocks x 256
// threads, 36.9 KB LDS.  Two-phase K staging (64+64), conflict-free lane-per-k
// sW mapping.  bf16 store halves the intermediate HBM write (28.8 -> 14.4 MB).
__global__ __launch_bounds__(256) void proj_gemm(
    const float* __restrict__ ent_emb,   // (N, 128) fp32, only rows <256 touched
    const float* __restrict__ rel_W,     // (237, 128, 128) fp32
    __bf16* __restrict__ proj)           // (237, 237, 128) bf16 (workspace, 14.4 MB)
{
  const int r   = blockIdx.y;
  const int m0  = blockIdx.x * 128;      // 0 or 128
  const int tid = threadIdx.x;

  __shared__ __bf16 sE[128 * LDSP];      // A: sE[m][k]   (row-major, k contiguous)
  __shared__ __bf16 sW[128 * LDSP];      // B^T: sW[n][k] = W[k][n]

  const int wave = tid >> 6;
  const int lane = tid & 63;
  const int lrow = lane & 15;
  const int quad = lane >> 4;
  const int r0 = wave * 32;              // wave's 32-row stripe

  floatx4 acc[2][8];
#pragma unroll
  for (int tr = 0; tr < 2; ++tr)
#pragma unroll
    for (int tc = 0; tc < 8; ++tc)
      acc[tr][tc] = (floatx4){0.f, 0.f, 0.f, 0.f};

  for (int kh = 0; kh < 2; ++kh) {
    if (kh) __syncthreads();             // MFMA reads of prev half done

    // --- stage E (fp32 -> bf16), 128 rows x 64 k ---
    {
      const int row  = tid >> 1;           // 0..127
      const int half = (tid & 1) * 32;     // k sub-offset
      const float* src = ent_emb + (size_t)(m0 + row) * D + kh * 64 + half;
      __bf16* dst = sE + row * LDSP + half;
#pragma unroll
      for (int i = 0; i < 8; ++i) {
        float4 v = ((const float4*)src)[i];
        bf16x4 pk = { (__bf16)v.x, (__bf16)v.y, (__bf16)v.z, (__bf16)v.w };
        *(bf16x4*)(dst + i * 4) = pk;
      }
    }
    // --- stage W transposed (fp32 -> bf16): sW[n][k] = W[kh*64+k][n] ---
    // lane-per-k: write bank = (4n + k/2)%32 spans all 32 banks, adjacent
    // lanes (k, k+1) merge in the same 4B word -> conflict-free.
    {
      const int k  = tid & 63;             // k within half (= lane)
      const int n0 = (tid >> 6) * 32;      // wave's 32-col chunk
      const float* src = rel_W + ((size_t)r * D + kh * 64 + k) * D + n0;
#pragma unroll
      for (int i = 0; i < 8; ++i) {
        float4 v = ((const float4*)src)[i];
        const int n = n0 + i * 4;
        sW[(n + 0) * LDSP + k] = (__bf16)v.x;
        sW[(n + 1) * LDSP + k] = (__bf16)v.y;
        sW[(n + 2) * LDSP + k] = (__bf16)v.z;
        sW[(n + 3) * LDSP + k] = (__bf16)v.w;
      }
    }
    __syncthreads();

    // --- MFMA: 2 k-steps of 32 over this half ---
#pragma unroll
    for (int kk = 0; kk < 2; ++kk) {
      const int k0 = kk * 32 + quad * 8;
      bf16x8 a[2], b[8];
#pragma unroll
      for (int tr = 0; tr < 2; ++tr)
        a[tr] = *(const bf16x8*)&sE[(r0 + tr * 16 + lrow) * LDSP + k0];
#pragma unroll
      for (int tc = 0; tc < 8; ++tc)
        b[tc] = *(const bf16x8*)&sW[(tc * 16 + lrow) * LDSP + k0];
#pragma unroll
      for (int tr = 0; tr < 2; ++tr)
#pragma unroll
        for (int tc = 0; tc < 8; ++tc)
          acc[tr][tc] = __builtin_amdgcn_mfma_f32_16x16x32_bf16(
              a[tr], b[tc], acc[tr][tc], 0, 0, 0);
    }
  }

  // --- store bf16: D[m][n], m = quad*4 + reg (verified layout), n = lrow ---
#pragma unroll
  for (int tr = 0; tr < 2; ++tr) {
    const int ebase = m0 + r0 + tr * 16 + quad * 4;
#pragma unroll
    for (int reg = 0; reg < 4; ++reg) {
      const int e = ebase + reg;
      if (e < NENT) {
        __bf16* dst = proj + ((size_t)r * NENT + e) * D;
#pragma unroll
        for (int tc = 0; tc < 8; ++tc)
          dst[tc * 16 + lrow] = (__bf16)acc[tr][tc][reg];
      }
    }
  }
}

// out[b] = fc_b + sum_{c,j} relu(w0[c]*ph[j] + w1[c]*re[j] + w2[c]*pt[j] + cb[c]) * fcw[c*128+j]
// One wave per triple.  Lane l handles j = 2l, 2l+1:
//  - ph/pt gathers: ONE dword (bf16x2) each, full row = 256 B coalesced
//  - re: one dwordx2 (f32)
//  - fc_w: LDS-staged float2 (r3's measured-best path), ds_read_b64 imm offset
//  - packed f32x2 math.  LDS 25.6 KB -> 6 blocks/CU.
__global__ __launch_bounds__(256) void conv_fc(
    const int*    __restrict__ triples,   // (B,3)
    const float*  __restrict__ rel_emb,   // (237,128)
    const float*  __restrict__ conv_w,    // (50,3)
    const float*  __restrict__ conv_b,    // (50)
    const float*  __restrict__ fc_w,      // (6400)
    const float*  __restrict__ fc_b,      // (1)
    const __bf16* __restrict__ proj,      // (237,237,128) bf16
    float*        __restrict__ out)       // (B,)
{
  const int tid  = threadIdx.x;
  const int wave = tid >> 6;
  const int lane = tid & 63;
  const int b    = blockIdx.x * 4 + wave;

  __shared__ float2 sFw[50 * 64];        // sFw[c*64+l] = fc_w[c*128 + 2l .. 2l+1]

  // issue this triple's gathers first -- latency hides under fc_w staging
  const int h = triples[b * 3 + 0];
  const int r = triples[b * 3 + 1];
  const int t = triples[b * 3 + 2];
  const __bf16* phb = proj + ((size_t)r * NENT + h) * D;
  const __bf16* ptb = proj + ((size_t)r * NENT + t) * D;
  const float*  rep = rel_emb + (size_t)r * D;
  const bf16x2 hph = *(const bf16x2*)(phb + 2 * lane);
  const bf16x2 hpt = *(const bf16x2*)(ptb + 2 * lane);
  const float2 vre_ = ((const float2*)rep)[lane];

  // cooperative fc_w -> LDS (linear coalesced copy, 3200 float2)
  const float2* fwsrc = (const float2*)fc_w;
  for (int i = tid; i < 3200; i += 256) sFw[i] = fwsrc[i];
  __syncthreads();

  f32x2 vph = { (float)hph.x, (float)hph.y };
  f32x2 vpt = { (float)hpt.x, (float)hpt.y };
  f32x2 vre = { vre_.x, vre_.y };

  f32x2 acc = (f32x2){0.f, 0.f};
#pragma unroll
  for (int c = 0; c < 50; ++c) {
    const float w0 = conv_w[c * 3 + 0];
    const float w1 = conv_w[c * 3 + 1];
    const float w2 = conv_w[c * 3 + 2];
    const float bc = conv_b[c];
    const float2 fwc = sFw[c * 64 + lane];          // ds_read_b64, imm offset
    f32x2 f = vph * w0 + vre * w1 + vpt * w2 + bc;  // packed fma chain
    f.x = fmaxf(f.x, 0.f);
    f.y = fmaxf(f.y, 0.f);
    acc.x = fmaf(f.x, fwc.x, acc.x);
    acc.y = fmaf(f.y, fwc.y, acc.y);
  }
  float a = acc.x + acc.y;
#pragma unroll
  for (int off = 32; off; off >>= 1) a += __shfl_down(a, off, 64);
  if (lane == 0) out[b] = a + fc_b[0];
}

extern "C" void kernel_launch(void* const* d_in, const int* in_sizes, int n_in,
                              void* d_out, int out_size, void* d_ws, size_t ws_size,
                              hipStream_t stream) {
  const int*   triples = (const int*)  d_in[0];
  const float* ent_emb = (const float*)d_in[1];
  const float* rel_emb = (const float*)d_in[2];
  const float* rel_W   = (const float*)d_in[3];
  const float* conv_w  = (const float*)d_in[4];
  const float* conv_b  = (const float*)d_in[5];
  const float* fc_w    = (const float*)d_in[6];
  const float* fc_b    = (const float*)d_in[7];
  float*  out  = (float*)d_out;
  __bf16* proj = (__bf16*)d_ws;          // 237*237*128 bf16 = 14.4 MB

  dim3 g1(2, NREL);
  proj_gemm<<<g1, 256, 0, stream>>>(ent_emb, rel_W, proj);
  conv_fc<<<B_TRIPLES / 4, 256, 0, stream>>>(triples, rel_emb, conv_w, conv_b,
                                             fc_w, fc_b, proj, out);
}